// Round 1
// baseline (331.587 us; speedup 1.0000x reference)
//
#include <hip/hip_runtime.h>
#include <hip/hip_bf16.h>
#include <stdint.h>

typedef unsigned short u16;
typedef short bf16x8 __attribute__((ext_vector_type(8)));
typedef float f32x4 __attribute__((ext_vector_type(4)));
typedef u16 u16x8 __attribute__((ext_vector_type(8)));

#define DEVFN static __device__ __forceinline__

// sizes
#define NB 16
#define CIN 256
#define HH 64
#define WW 64
#define COUT 512
#define NEXP 8
#define NPX 4096           // 64*64
#define KTOT 2304          // 256*9
#define NSTEP 72           // 8 ci-blocks * 9 shifts

DEVFN u16 bf16_rne(float f){
  union { float f; uint32_t u; } v; v.f = f;
  uint32_t u = v.u;
  return (u16)((u + 0x7fffu + ((u >> 16) & 1u)) >> 16);
}

DEVFN void gload16(const void* g, void* l){
  __builtin_amdgcn_global_load_lds((const __attribute__((address_space(1))) void*)g,
                                   (__attribute__((address_space(3))) void*)l,
                                   16, 0, 0);
}

// ---------------- pooled = mean over HW ----------------
__global__ void k_pool(const float* __restrict__ x, float* __restrict__ pooled){
  int bc = blockIdx.x;                       // 0..4095 = b*256+c
  const float4* p4 = (const float4*)(x + (size_t)bc * NPX);
  int t = threadIdx.x;
  float s = 0.f;
  for (int i = t; i < NPX/4; i += 256){ float4 v = p4[i]; s += v.x+v.y+v.z+v.w; }
  for (int o = 32; o; o >>= 1) s += __shfl_down(s, o);
  __shared__ float ls[4];
  if ((t & 63) == 0) ls[t >> 6] = s;
  __syncthreads();
  if (t == 0) pooled[bc] = (ls[0]+ls[1]+ls[2]+ls[3]) * (1.0f/ (float)NPX);
}

// ---------------- routing = sigmoid(pooled @ fcw^T + fcb) ----------------
__global__ void k_route(const float* __restrict__ pooled, const float* __restrict__ fcw,
                        const float* __restrict__ fcb, float* __restrict__ routing){
  int bk = blockIdx.x;              // 0..127
  int b = bk >> 3, k = bk & 7;
  int l = threadIdx.x;              // 64
  float4 pv = ((const float4*)(pooled + b*CIN))[l];
  float4 wv = ((const float4*)(fcw   + k*CIN))[l];
  float s = pv.x*wv.x + pv.y*wv.y + pv.z*wv.z + pv.w*wv.w;
  for (int o = 32; o; o >>= 1) s += __shfl_down(s, o);
  if (l == 0) routing[b*8 + k] = 1.0f / (1.0f + __expf(-(s + fcb[k])));
}

// ---------------- combined bias ----------------
__global__ void k_cbias(const float* __restrict__ routing, const float* __restrict__ eb,
                        float* __restrict__ cbias){
  int idx = blockIdx.x*256 + threadIdx.x;   // 8192 = b*512+co
  int b = idx >> 9, co = idx & 511;
  float s = 0.f;
  for (int k = 0; k < 8; k++) s += routing[b*8+k] * eb[k*COUT + co];
  cbias[idx] = s;
}

// ---------------- combined weights -> bf16, layout [b][step][co][ci32] ----------------
__global__ void k_wcomb(const float* __restrict__ routing, const float* __restrict__ ew,
                        u16* __restrict__ wc){
  int blk  = blockIdx.x;            // 72*64 = 4608
  int step = blk >> 6;              // 0..71
  int cog  = blk & 63;
  int cb = step / 9, rs = step - cb*9;
  int t = threadIdx.x;
  int ci = t & 31, co = cog*8 + (t >> 5);
  int cig = cb*32 + ci;
  float wv[8];
#pragma unroll
  for (int k = 0; k < 8; k++)
    wv[k] = ew[(size_t)((k*COUT + co)*CIN + cig)*9 + rs];
  for (int b = 0; b < NB; b++){
    float s = 0.f;
#pragma unroll
    for (int k = 0; k < 8; k++) s += routing[b*8+k] * wv[k];
    wc[((size_t)(b*NSTEP + step)*COUT + co)*32 + ci] = bf16_rne(s);
  }
}

// ---------------- x -> padded transposed bf16: x_t[b][66][68][256] ----------------
__global__ void k_xprep(const float* __restrict__ x, u16* __restrict__ xt){
  int blk = blockIdx.x;             // 16*64*4 = 4096
  int ctile = blk & 3;
  int h = (blk >> 2) & 63;
  int b = blk >> 8;
  __shared__ u16 S[64][66];
  int t = threadIdx.x;
  {
    int ci_l = t >> 2, w0 = (t & 3) * 16;
    const float4* src = (const float4*)(x + ((size_t)((b*CIN + ctile*64 + ci_l)*HH + h)*WW + w0));
    float4 a = src[0], bb = src[1], c = src[2], d = src[3];
    u16* row = &S[ci_l][w0];
    row[0]=bf16_rne(a.x);  row[1]=bf16_rne(a.y);  row[2]=bf16_rne(a.z);  row[3]=bf16_rne(a.w);
    row[4]=bf16_rne(bb.x); row[5]=bf16_rne(bb.y); row[6]=bf16_rne(bb.z); row[7]=bf16_rne(bb.w);
    row[8]=bf16_rne(c.x);  row[9]=bf16_rne(c.y);  row[10]=bf16_rne(c.z); row[11]=bf16_rne(c.w);
    row[12]=bf16_rne(d.x); row[13]=bf16_rne(d.y); row[14]=bf16_rne(d.z); row[15]=bf16_rne(d.w);
  }
  __syncthreads();
  {
    int w_l = t >> 2, cig = (t & 3) * 16;
    u16x8 v0, v1;
#pragma unroll
    for (int j = 0; j < 8; j++){ v0[j] = S[cig+j][w_l]; v1[j] = S[cig+8+j][w_l]; }
    u16* dst = xt + ((size_t)(b*66 + h + 1)*68 + (w_l + 1))*CIN + ctile*64 + cig;
    *(u16x8*)(dst)     = v0;
    *(u16x8*)(dst + 8) = v1;
  }
}

// ---------------- the conv: implicit GEMM, 128co x 128px tiles ----------------
#define XBYTES 17408      // 4*68*32*2
#define WBYTES 8192       // 128*32*2

__global__ __launch_bounds__(256, 2) void k_conv(
    const u16* __restrict__ xt, const u16* __restrict__ wc,
    const float* __restrict__ cbias, float* __restrict__ out,
    float* __restrict__ ssum, float* __restrict__ ssq)
{
  __shared__ char lds[2*XBYTES + 2*WBYTES];
  char* Xb0 = lds;
  char* Xb1 = lds + XBYTES;
  char* Wb0 = lds + 2*XBYTES;
  char* Wb1 = lds + 2*XBYTES + WBYTES;

  int hw = blockIdx.x;                       // 2048 blocks
  int lb = (hw & 7) * 256 + (hw >> 3);       // XCD-aware swizzle (2048%8==0, bijective)
  int b  = lb >> 7;
  int ct = (lb >> 5) & 3;
  int pt = lb & 31;
  int h0 = pt * 2;

  int t = threadIdx.x, l = t & 63, wv = t >> 6;
  int wm = wv >> 1, wn = wv & 1;
  int l15 = l & 15, kbq = l >> 4;

  const u16* xtb = xt + (size_t)b * 66*68*CIN;
  const u16* wcb = wc + (size_t)(b*NSTEP) * COUT*32 + ct*128*32;

  // ---- staging helpers (inlined logic) ----
  // W: 512 16B-chunks per step tile; chunk q -> row co_l=q>>2, sub j=q&3, src chunk j^((co_l>>1)&3)
  // X: 1088 chunks ([4 rows][68 cols][4 sub]); src chunk j^((c>>1)&3)

  f32x4 acc[4][4];
#pragma unroll
  for (int m = 0; m < 4; m++)
#pragma unroll
    for (int n = 0; n < 4; n++) acc[m][n] = (f32x4){0.f,0.f,0.f,0.f};

  const int byteA0 = (wm*64 + l15)*64 + ((kbq ^ ((l15 >> 1) & 3)) << 4);

  // prologue: stage X(cb=0) and W(step=0)
  {
    // X
#pragma unroll
    for (int i = 0; i < 5; i++){
      int qb = i*256 + wv*64;
      if (qb < 1088){
        int q = qb + l;
        int t2 = q >> 2;
        int lr = (t2 * 964) >> 16;
        int c  = t2 - lr*68;
        int j  = q & 3;
        const u16* src = xtb + ((size_t)(h0 + lr)*68 + c)*CIN + 0*32 + ((j ^ ((c >> 1) & 3)) << 3);
        gload16(src, Xb0 + qb*16);
      }
    }
    // W
#pragma unroll
    for (int i = 0; i < 2; i++){
      int q = i*256 + wv*64 + l;
      int co_l = q >> 2, j = q & 3;
      const u16* src = wcb + co_l*32 + ((j ^ ((co_l >> 1) & 3)) << 3);
      gload16(src, Wb0 + (i*256 + wv*64)*16);
    }
  }
  __syncthreads();

  int step = 0;
  for (int cb = 0; cb < 8; cb++){
    char* Xc = (cb & 1) ? Xb1 : Xb0;
    char* Xn = (cb & 1) ? Xb0 : Xb1;
#pragma unroll
    for (int rs = 0; rs < 9; rs++, step++){
      const int r = rs / 3, s = rs - r*3;
      // stage next W tile into other buffer
      if (step < NSTEP-1){
        char* Wn = ((step+1) & 1) ? Wb1 : Wb0;
        const u16* wstep = wcb + (size_t)(step+1)*COUT*32;
#pragma unroll
        for (int i = 0; i < 2; i++){
          int q = i*256 + wv*64 + l;
          int co_l = q >> 2, j = q & 3;
          gload16(wstep + co_l*32 + ((j ^ ((co_l >> 1) & 3)) << 3),
                  Wn + (i*256 + wv*64)*16);
        }
      }
      // stage next X block (once per ci-block, in its last shift-step)
      if (rs == 8 && cb < 7){
#pragma unroll
        for (int i = 0; i < 5; i++){
          int qb = i*256 + wv*64;
          if (qb < 1088){
            int q = qb + l;
            int t2 = q >> 2;
            int lr = (t2 * 964) >> 16;
            int c  = t2 - lr*68;
            int j  = q & 3;
            const u16* src = xtb + ((size_t)(h0 + lr)*68 + c)*CIN + (cb+1)*32 + ((j ^ ((c >> 1) & 3)) << 3);
            gload16(src, Xn + qb*16);
          }
        }
      }

      // fragments + MFMA
      char* Wc = (step & 1) ? Wb1 : Wb0;
      int c0 = l15 + s;
      int byteB0 = ((wn + r)*68 + c0)*64 + ((kbq ^ ((c0 >> 1) & 3)) << 4);

      bf16x8 af[4], bfr[4];
#pragma unroll
      for (int m = 0; m < 4; m++) af[m]  = *(const bf16x8*)(Wc + byteA0 + m*1024);
#pragma unroll
      for (int n = 0; n < 4; n++) bfr[n] = *(const bf16x8*)(Xc + byteB0 + n*1024);
#pragma unroll
      for (int m = 0; m < 4; m++)
#pragma unroll
        for (int n = 0; n < 4; n++)
          acc[m][n] = __builtin_amdgcn_mfma_f32_16x16x32_bf16(af[m], bfr[n], acc[m][n], 0, 0, 0);

      __syncthreads();
    }
  }

  // ---- epilogue: bias add, store raw, fused BN partial sums ----
  int co_t = ct*128 + wm*64 + (kbq << 2);
  int px_t = pt*128 + wn*64 + l15;
  float* outb = out + (size_t)b * COUT * NPX;
#pragma unroll
  for (int m = 0; m < 4; m++){
#pragma unroll
    for (int rg = 0; rg < 4; rg++){
      int co = co_t + m*16 + rg;
      float bias = cbias[b*COUT + co];
      float s1 = 0.f, s2 = 0.f;
      size_t base = (size_t)co * NPX + px_t;
#pragma unroll
      for (int n = 0; n < 4; n++){
        float v = acc[m][n][rg] + bias;
        outb[base + n*16] = v;
        s1 += v; s2 += v*v;
      }
#pragma unroll
      for (int o = 8; o; o >>= 1){ s1 += __shfl_xor(s1, o); s2 += __shfl_xor(s2, o); }
      if (l15 == 0){ atomicAdd(&ssum[co], s1); atomicAdd(&ssq[co], s2); }
    }
  }
}

// ---------------- finalize BN scale/shift ----------------
__global__ void k_stats(const float* __restrict__ ssum, const float* __restrict__ ssq,
                        const float* __restrict__ gamma, const float* __restrict__ beta,
                        float* __restrict__ sc, float* __restrict__ sh){
  int co = blockIdx.x*256 + threadIdx.x;    // 512
  const float invN = 1.0f / 65536.0f;
  float m  = ssum[co] * invN;
  float var = ssq[co] * invN - m*m;
  float scale = gamma[co] * rsqrtf(var + 1e-5f);
  sc[co] = scale;
  sh[co] = beta[co] - m*scale;
}

// ---------------- normalize + LeakyReLU (in place on d_out) ----------------
__global__ void k_norm(float* __restrict__ out, const float* __restrict__ sc,
                       const float* __restrict__ sh){
  const int NF4 = (NB*COUT*NPX)/4;          // 8388608
  int idx = blockIdx.x*256 + threadIdx.x;   // grid 8192*256
  float4* o4 = (float4*)out;
  for (int i = idx; i < NF4; i += 8192*256){
    float4 v = o4[i];
    int co = (i >> 10) & 511;
    float a = sc[co], d = sh[co];
    v.x = fmaf(v.x, a, d); v.y = fmaf(v.y, a, d);
    v.z = fmaf(v.z, a, d); v.w = fmaf(v.w, a, d);
    v.x = v.x > 0.f ? v.x : 0.1f*v.x;
    v.y = v.y > 0.f ? v.y : 0.1f*v.y;
    v.z = v.z > 0.f ? v.z : 0.1f*v.z;
    v.w = v.w > 0.f ? v.w : 0.1f*v.w;
    o4[i] = v;
  }
}

extern "C" void kernel_launch(void* const* d_in, const int* in_sizes, int n_in,
                              void* d_out, int out_size, void* d_ws, size_t ws_size,
                              hipStream_t stream) {
  const float* x     = (const float*)d_in[0];
  const float* ew    = (const float*)d_in[1];
  const float* eb    = (const float*)d_in[2];
  const float* fcw   = (const float*)d_in[3];
  const float* fcb   = (const float*)d_in[4];
  const float* gamma = (const float*)d_in[5];
  const float* beta  = (const float*)d_in[6];
  float* out = (float*)d_out;

  char* ws = (char*)d_ws;
  const size_t XT_BYTES = (size_t)NB*66*68*CIN*2;          // 36,765,696
  const size_t WC_BYTES = (size_t)NB*NSTEP*COUT*32*2;      // 37,748,736
  u16* xt = (u16*)ws;
  u16* wc = (u16*)(ws + XT_BYTES);
  float* fbase   = (float*)(ws + XT_BYTES + WC_BYTES);
  float* pooled  = fbase;                 // 4096
  float* routing = fbase + 4096;          // 128
  float* cbias   = fbase + 4096 + 128;    // 8192
  float* ssum    = cbias + 8192;          // 512
  float* ssq     = ssum + 512;            // 512
  float* sc      = ssq + 512;             // 512
  float* sh      = sc + 512;              // 512

  hipMemsetAsync(xt, 0, XT_BYTES, stream);
  hipMemsetAsync(ssum, 0, 2*512*sizeof(float), stream);

  k_pool <<<4096, 256, 0, stream>>>(x, pooled);
  k_xprep<<<4096, 256, 0, stream>>>(x, xt);
  k_route<<<128,   64, 0, stream>>>(pooled, fcw, fcb, routing);
  k_cbias<<<32,   256, 0, stream>>>(routing, eb, cbias);
  k_wcomb<<<4608, 256, 0, stream>>>(routing, ew, wc);
  k_conv <<<2048, 256, 0, stream>>>(xt, wc, cbias, out, ssum, ssq);
  k_stats<<<2,    256, 0, stream>>>(ssum, ssq, gamma, beta, sc, sh);
  k_norm <<<8192, 256, 0, stream>>>(out, sc, sh);
}